// Round 9
// baseline (173.357 us; speedup 1.0000x reference)
//
#include <hip/hip_runtime.h>
#include <math.h>
#include <stdint.h>

#define NEXP 48
#define NCAT 30
#define SP_TOT 13440            // 24*28*20
#define M_TOT (NCAT * SP_TOT)   // 403200
#define CPB 128                 // columns per block (2 threads/col, 256 thr)
#define PITCH 25                // LDS row pitch in floats (24 + 1 pad)

// R8's verified 2-thread/column bitonic selection, with the load structure
// fixed: g is LDS-staged via coalesced 256B loads (R2's proven pattern);
// own-se strided loads are issued BEFORE the sort and consumed after.
// Exactness: boundary-tie count check -> exact stable u64-rank fallback
// == jax.lax.top_k semantics. General K.
__global__ __launch_bounds__(256) void moe_topk_contract(
    const float* __restrict__ gm, const float* __restrict__ gf,
    const float* __restrict__ se, const int* __restrict__ kptr,
    float* __restrict__ out)
{
    __shared__ float A[256 * PITCH];        // 25.6 KB

    const int tid     = threadIdx.x;
    const int colbase = blockIdx.x * CPB;
    const int col_loc = tid >> 1;           // 0..127
    const int sub     = tid & 1;            // expert half
    const int col     = colbase + col_loc;
    const int K       = *kptr;
    const float sgnf  = sub ? -1.f : 1.f;
    const int myrow   = col_loc + 128 * sub;   // own LDS row (half-blocked)
    const int c       = tid & 127;             // staging column
    const int ehi     = tid >> 7;              // staging expert half (wave-uniform)
    const int strow   = c + 128 * ehi;         // staging LDS row

    #pragma unroll 1
    for (int t = 0; t < 2; ++t) {
        const float* __restrict__ g_ = t ? gf : gm;

        // ---- stage 48 experts x 128 cols: coalesced 256B per load instr
        {
            float stg[24];
            #pragma unroll
            for (int rep = 0; rep < 24; ++rep)
                stg[rep] = g_[(ehi * 24 + rep) * M_TOT + colbase + c];
            #pragma unroll
            for (int rep = 0; rep < 24; ++rep)
                A[strow * PITCH + rep] = stg[rep];
        }
        __syncthreads();

        // ---- own 24 |g| -> s[32] (signed g NOT kept; re-read at FMA)
        float s[32];
        #pragma unroll
        for (int k = 0; k < 24; ++k)
            s[k] = sgnf * fabsf(A[myrow * PITCH + k]);
        #pragma unroll
        for (int k = 24; k < 32; ++k)
            s[k] = sgnf * -INFINITY;

        // ---- own se: strided loads issued NOW, consumed after the sort
        float sev[24];
        #pragma unroll
        for (int k = 0; k < 24; ++k)
            sev[k] = se[(sub * 24 + k) * M_TOT + col];

        float tau = 0.f;
        if (K == 24) {
            // local bitonic sort, ascending in stored space (compile-time net)
            #pragma unroll
            for (int kk = 2; kk <= 32; kk <<= 1) {
                #pragma unroll
                for (int j = kk >> 1; j > 0; j >>= 1) {
                    #pragma unroll
                    for (int i = 0; i < 32; ++i) {
                        const int l = i ^ j;
                        if (l > i) {
                            const float lo = fminf(s[i], s[l]);
                            const float hi = fmaxf(s[i], s[l]);
                            if ((i & kk) == 0) { s[i] = lo; s[l] = hi; }
                            else               { s[i] = hi; s[l] = lo; }
                        }
                    }
                }
            }
            // cross-thread step of the 64-element merge (uniform both subs)
            #pragma unroll
            for (int k = 0; k < 32; ++k)
                s[k] = fminf(s[k], -__shfl_xor(s[k], 1));
            // local ascending bitonic merge (j = 16..1)
            #pragma unroll
            for (int j = 16; j > 0; j >>= 1) {
                #pragma unroll
                for (int i = 0; i < 32; ++i) {
                    const int l = i ^ j;
                    if (l > i) {
                        const float lo = fminf(s[i], s[l]);
                        s[l] = fmaxf(s[i], s[l]);
                        s[i] = lo;
                    }
                }
            }
            // tau lives in thread sub=1, slot 23 (stored negated)
            const float o23 = __shfl_xor(s[23], 1);
            tau = -(sub ? s[23] : o23);
        }

        // ---- masked FMA (signed g re-read from LDS) + boundary-tie counts
        float acc = 0.f;
        int cgt = 0, cge = 0;
        if (K == 24) {
            #pragma unroll
            for (int k = 0; k < 24; ++k) {
                const float gk = A[myrow * PITCH + k];
                const float a  = fabsf(gk);
                cgt += (a > tau)  ? 1 : 0;
                cge += (a >= tau) ? 1 : 0;
                acc = (a >= tau) ? fmaf(gk, sev[k], acc) : acc;
            }
            cgt += __shfl_xor(cgt, 1);
            cge += __shfl_xor(cge, 1);
        }

        const bool bad = (K != 24) || (cgt != 23) || (cge != 24);
        if (__any(bad)) {
            // exact stable-rank fallback (boundary |value| tie or generic K)
            if (bad) {
                acc = 0.f;
                if (sub == 0) {
                    #pragma unroll 1
                    for (int i2 = 0; i2 < NEXP; ++i2) {
                        const float gi = g_[i2 * M_TOT + col];
                        const uint64_t ki =
                            ((uint64_t)(__float_as_uint(gi) & 0x7fffffffu) << 32)
                            | (uint32_t)(NEXP - 1 - i2);
                        int r = 0;
                        #pragma unroll 1
                        for (int j2 = 0; j2 < NEXP; ++j2) {
                            const float gj = g_[j2 * M_TOT + col];
                            const uint64_t kj =
                                ((uint64_t)(__float_as_uint(gj) & 0x7fffffffu) << 32)
                                | (uint32_t)(NEXP - 1 - j2);
                            r += (kj > ki) ? 1 : 0;
                        }
                        if (r < K) acc = fmaf(gi, se[i2 * M_TOT + col], acc);
                    }
                }
            }
        }

        acc += __shfl_xor(acc, 1);
        if (sub == 0) out[t * M_TOT + col] = acc;
        __syncthreads();   // A is overwritten by next t's stage
    }
}

// Kernel 2: in-place softmax over the category dim (stride SP_TOT).
__global__ __launch_bounds__(256) void softmax_c(float* __restrict__ out)
{
    const int q = blockIdx.x * blockDim.x + threadIdx.x;
    if (q >= 2 * SP_TOT) return;
    const int t  = q / SP_TOT;
    const int sp = q - t * SP_TOT;
    float* __restrict__ base = out + t * M_TOT + sp;

    float v[NCAT];
    float mx = -INFINITY;
    #pragma unroll
    for (int c = 0; c < NCAT; ++c) {
        v[c] = base[c * SP_TOT];
        mx = fmaxf(mx, v[c]);
    }
    float sum = 0.f;
    #pragma unroll
    for (int c = 0; c < NCAT; ++c) {
        v[c] = __expf(v[c] - mx);
        sum += v[c];
    }
    const float inv = 1.f / sum;
    #pragma unroll
    for (int c = 0; c < NCAT; ++c)
        base[c * SP_TOT] = v[c] * inv;
}

extern "C" void kernel_launch(void* const* d_in, const int* in_sizes, int n_in,
                              void* d_out, int out_size, void* d_ws, size_t ws_size,
                              hipStream_t stream) {
    const float* gm   = (const float*)d_in[0];
    const float* gf   = (const float*)d_in[1];
    const float* se   = (const float*)d_in[2];
    const int*   kptr = (const int*)d_in[3];
    float* out = (float*)d_out;

    const int grid1 = M_TOT / CPB;                 // 3150 blocks
    moe_topk_contract<<<grid1, 256, 0, stream>>>(gm, gf, se, kptr, out);

    const int grid2 = (2 * SP_TOT + 255) / 256;    // 105
    softmax_c<<<grid2, 256, 0, stream>>>(out);
}